// Round 14
// baseline (392.015 us; speedup 1.0000x reference)
//
#include <hip/hip_runtime.h>
#include <cmath>

// ---- problem constants ----
#define DIMC   256
#define L_WIN  1023        // (131072-256)/128 + 1
#define M_VALID 4092       // 4*1023 tokens
#define M_PAD  4096
#define DI     1024        // D_INNER
#define TLEN   131072
#define SEG    32          // scan segment length
#define NSEG   32          // 32*32 = 1024 >= 1023

typedef __bf16 bf16x8 __attribute__((ext_vector_type(8)));
typedef __bf16 bf16x4 __attribute__((ext_vector_type(4)));
typedef float  f32x4  __attribute__((ext_vector_type(4)));

__device__ __forceinline__ float sigmoidf_(float x){ return 1.f/(1.f + __expf(-x)); }
__device__ __forceinline__ float softplusf_(float v){ return fmaxf(v,0.f) + log1pf(__expf(-fabsf(v))); }

// DPP rotate-add: pure-VALU cross-lane sum step (no LDS traffic)
template<int CTRL>
__device__ __forceinline__ float dpp_add(float x){
  int v = __builtin_amdgcn_update_dpp(0, __builtin_bit_cast(int, x), CTRL, 0xF, 0xF, true);
  return x + __builtin_bit_cast(float, v);
}

// ---------------- init: frame (blocks 0..4095) + weight bf16 convert (blocks 4096+) ----------------
__global__ __launch_bounds__(256) void init_kernel(const float* __restrict__ x, float* __restrict__ res,
    const float* __restrict__ a, __bf16* __restrict__ da, int na,
    const float* __restrict__ b, __bf16* __restrict__ db, int nb,
    const float* __restrict__ c, __bf16* __restrict__ dc, int nc)
{
  if (blockIdx.x < M_PAD){
    int m = blockIdx.x, j = threadIdx.x;
    float v = 0.f;
    if (m < M_VALID){
      int bb = m / L_WIN, l = m - bb*L_WIN;
      v = x[(size_t)bb*TLEN + l*128 + j];
    }
    res[(size_t)m*DIMC + j] = v;
    return;
  }
  int nblk = gridDim.x - M_PAD;
  int stride = nblk*256;
  int base = (blockIdx.x - M_PAD)*256 + threadIdx.x;
  for (int i = base; i < na; i += stride) da[i] = (__bf16)a[i];
  for (int i = base; i < nb; i += stride) db[i] = (__bf16)b[i];
  for (int i = base; i < nc; i += stride) dc[i] = (__bf16)c[i];
}

// ---------------- rmsnorm row of 256 -> bf16 ----------------
__global__ __launch_bounds__(256) void rms_kernel(const float* __restrict__ src, __bf16* __restrict__ dst,
                                                  const float* __restrict__ w){
  int m = blockIdx.x, j = threadIdx.x;
  float v = (m < M_VALID) ? src[(size_t)m*DIMC + j] : 0.f;
  float s = v*v;
  #pragma unroll
  for (int off = 32; off; off >>= 1) s += __shfl_down(s, off);
  __shared__ float ls[4];
  if ((threadIdx.x & 63) == 0) ls[threadIdx.x >> 6] = s;
  __syncthreads();
  float tot = ls[0] + ls[1] + ls[2] + ls[3];
  float scale = rsqrtf(tot * (1.f/DIMC) + 1e-5f);
  dst[(size_t)m*DIMC + j] = (__bf16)(v * scale * w[j]);
}

// ======== LDS-tiled bf16 MFMA GEMM: C[M x N] = A[M x K] * B[N x K]^T (+addsrc) ========
// NOTE: C/addsrc NOT __restrict__ — out_proj call is in-place (C==addsrc).
template<int WM, int WN, typename OutT>
__global__ __launch_bounds__(256) void gemm_tiled_kernel(const __bf16* __restrict__ A, const __bf16* __restrict__ B,
    OutT* C, const float* addsrc, int K, int ldc)
{
  constexpr int BM  = 32*WM;
  constexpr int BN  = 32*WN;
  constexpr int LDK = 72;
  __shared__ __bf16 As[BM*LDK];
  __shared__ __bf16 Bs[BN*LDK];
  int tid  = threadIdx.x;
  int lane = tid & 63, wv = tid >> 6;
  int row  = lane & 15, kq = lane >> 4;
  int m0 = blockIdx.x*BM, n0 = blockIdx.y*BN;
  int wmo = (wv >> 1)*(16*WM);
  int wno = (wv &  1)*(16*WN);
  f32x4 acc[WM][WN] = {};
  for (int kt = 0; kt < K; kt += 64){
    __syncthreads();
    #pragma unroll
    for (int r = 0; r < BM/32; ++r){
      int seg = r*256 + tid;
      int rw = seg >> 3, sb = seg & 7;
      *(bf16x8*)(As + rw*LDK + sb*8) = *(const bf16x8*)(A + (size_t)(m0 + rw)*K + kt + sb*8);
    }
    #pragma unroll
    for (int r = 0; r < BN/32; ++r){
      int seg = r*256 + tid;
      int rw = seg >> 3, sb = seg & 7;
      *(bf16x8*)(Bs + rw*LDK + sb*8) = *(const bf16x8*)(B + (size_t)(n0 + rw)*K + kt + sb*8);
    }
    __syncthreads();
    #pragma unroll
    for (int ks = 0; ks < 2; ++ks){
      bf16x8 af[WM], bfr[WN];
      #pragma unroll
      for (int i = 0; i < WM; ++i) af[i]  = *(const bf16x8*)(As + (wmo + i*16 + row)*LDK + ks*32 + kq*8);
      #pragma unroll
      for (int j = 0; j < WN; ++j) bfr[j] = *(const bf16x8*)(Bs + (wno + j*16 + row)*LDK + ks*32 + kq*8);
      #pragma unroll
      for (int i = 0; i < WM; ++i){
        #pragma unroll
        for (int j = 0; j < WN; ++j)
          acc[i][j] = __builtin_amdgcn_mfma_f32_16x16x32_bf16(af[i], bfr[j], acc[i][j], 0, 0, 0);
      }
    }
  }
  #pragma unroll
  for (int i = 0; i < WM; ++i){
    int cm = m0 + wmo + i*16 + kq*4;
    #pragma unroll
    for (int j = 0; j < WN; ++j){
      int cn = n0 + wno + j*16 + row;
      #pragma unroll
      for (int ii = 0; ii < 4; ++ii){
        size_t idx = (size_t)(cm + ii)*ldc + cn;
        float v = acc[i][j][ii];
        if (addsrc) v += addsrc[idx];
        C[idx] = (OutT)v;
      }
    }
  }
}

// ======== fused conv4+SiLU -> xproj MFMA -> dt_proj+softplus (r11 version, unchanged) ========
__global__ __launch_bounds__(256) void conv_xproj_dt_kernel(
  const __bf16* __restrict__ xz16, const float* __restrict__ cw, const float* __restrict__ cb,
  const __bf16* __restrict__ wxp, const float* __restrict__ dtw, const float* __restrict__ dtb,
  __bf16* __restrict__ u16, float* __restrict__ xdbl, __bf16* __restrict__ delta16)
{
  __shared__ __bf16 su[16][1032];   // +8 pad
  __shared__ float  sdt[16][17];
  int tid = threadIdx.x;
  int m0 = blockIdx.x * 16;
  // ---- phase A: causal depthwise conv4 + bias + SiLU ----
  {
    int d = tid * 4;
    float w[4][4], bias[4];
    #pragma unroll
    for (int c = 0; c < 4; ++c){
      #pragma unroll
      for (int j = 0; j < 4; ++j) w[c][j] = cw[(d + c)*4 + j];
      bias[c] = cb[d + c];
    }
    for (int ti = 0; ti < 16; ++ti){
      int m = m0 + ti;
      float acc[4] = {0.f, 0.f, 0.f, 0.f};
      if (m < M_VALID){
        int b = m / L_WIN;
        int l = m - b*L_WIN;
        #pragma unroll
        for (int c = 0; c < 4; ++c) acc[c] = bias[c];
        #pragma unroll
        for (int k = 0; k < 4; ++k){
          if (l >= k){
            bf16x4 xv = *(const bf16x4*)(xz16 + (size_t)(m - k)*2048 + d);
            #pragma unroll
            for (int c = 0; c < 4; ++c) acc[c] = fmaf((float)xv[c], w[c][3-k], acc[c]);
          }
        }
        #pragma unroll
        for (int c = 0; c < 4; ++c) acc[c] = acc[c] * sigmoidf_(acc[c]);
      }
      bf16x4 o;
      #pragma unroll
      for (int c = 0; c < 4; ++c) o[c] = (__bf16)acc[c];
      *(bf16x4*)(u16 + (size_t)m*DI + d) = o;
      *(bf16x4*)(&su[ti][d]) = o;
    }
  }
  __syncthreads();
  // ---- phase B: xproj, 16 tokens x 48 outputs, K=1024 ----
  {
    int lane = tid & 63, wv = tid >> 6;
    if (wv < 3){
      int row = lane & 15, kq = lane >> 4;
      f32x4 acc = {0.f, 0.f, 0.f, 0.f};
      const __bf16* Bp = wxp + (size_t)(wv*16 + row)*1024 + kq*8;
      for (int k = 0; k < 1024; k += 32){
        bf16x8 a  = *(const bf16x8*)(&su[row][k + kq*8]);
        bf16x8 bb = *(const bf16x8*)(Bp + k);
        acc = __builtin_amdgcn_mfma_f32_16x16x32_bf16(a, bb, acc, 0, 0, 0);
      }
      #pragma unroll
      for (int i = 0; i < 4; ++i){
        int tok = kq*4 + i;
        xdbl[(size_t)(m0 + tok)*48 + wv*16 + row] = acc[i];
        if (wv == 0) sdt[tok][row] = acc[i];
      }
    }
  }
  __syncthreads();
  // ---- phase C: dt_proj (K=16) + softplus -> delta16 ----
  {
    int d0 = tid * 4;
    float w[4][16], bias[4];
    #pragma unroll
    for (int c = 0; c < 4; ++c){
      #pragma unroll
      for (int q = 0; q < 16; ++q) w[c][q] = dtw[(d0 + c)*16 + q];
      bias[c] = dtb[d0 + c];
    }
    for (int t = 0; t < 16; ++t){
      float acc[4] = {bias[0], bias[1], bias[2], bias[3]};
      #pragma unroll
      for (int r = 0; r < 16; ++r){
        float dv = sdt[t][r];
        #pragma unroll
        for (int c = 0; c < 4; ++c) acc[c] = fmaf(dv, w[c][r], acc[c]);
      }
      bf16x4 o;
      #pragma unroll
      for (int c = 0; c < 4; ++c) o[c] = (__bf16)softplusf_(acc[c]);
      *(bf16x4*)(delta16 + (size_t)(m0 + t)*DI + d0) = o;
    }
  }
}

// ================= chunked two-phase selective scan =================
__global__ __launch_bounds__(256) void scan_part1_kernel(
  const __bf16* __restrict__ u16, const __bf16* __restrict__ delta16,
  const float* __restrict__ xdbl, const float* __restrict__ Alog, float2* __restrict__ Pq)
{
  int bid = blockIdx.x;
  int s = bid & 31, dtile = (bid >> 5) & 63, b = bid >> 11;
  int d0 = dtile << 4;
  int tid = threadIdx.x;
  int c = tid >> 4, n = tid & 15;
  float A_dn = -__expf(Alog[(d0 + c)*16 + n]);
  __shared__ float2 sdd[16][SEG+2];   // (dlt, dlt*u)
  __shared__ float  sB [SEG][17];
  int t0 = s*SEG;
  int nt = L_WIN - t0; if (nt > SEG) nt = SEG;
  size_t base_m = (size_t)b*L_WIN + t0;
  for (int i2 = tid; i2 < 16*SEG; i2 += 256){
    int tt = i2 >> 4, dd = i2 & 15;
    float dlt = 0.f, du = 0.f, Bv = 0.f;
    if (tt < nt){
      size_t m = base_m + tt;
      dlt = (float)delta16[m*DI + d0 + dd];
      du  = dlt * (float)u16[m*DI + d0 + dd];
      Bv  = xdbl[m*48 + 16 + dd];
    }
    sdd[dd][tt] = make_float2(dlt, du);
    sB[tt][dd]  = Bv;
  }
  __syncthreads();
  float h = 0.f, P = 1.f;
  #pragma unroll 8
  for (int t = 0; t < SEG; ++t){
    float2 dd2 = sdd[c][t];
    float dA = __expf(dd2.x * A_dn);
    h = fmaf(dA, h, dd2.y * sB[t][n]);
    P *= dA;
  }
  Pq[(((size_t)b*NSEG + s) << 14) + d0*16 + tid] = make_float2(P, h);
}

// r14: hstart computed inline by folding predecessor Pq entries (same order as the
// old combine kernel -> bit-identical). Removes the combine dispatch + hstart buffer.
// Safe: Pq fully written by scan_part1 (kernel boundary), no cross-block spin.
__global__ __launch_bounds__(256) void scan_part2_kernel(
  const __bf16* __restrict__ u16, const __bf16* __restrict__ delta16,
  const float* __restrict__ xdbl, const __bf16* __restrict__ xz16,
  const float* __restrict__ Alog, const float* __restrict__ Dp,
  const float2* __restrict__ Pq, __bf16* __restrict__ y16)
{
  int bid = blockIdx.x;
  int s = bid & 31, dtile = (bid >> 5) & 63, b = bid >> 11;
  int d0 = dtile << 4;
  int tid = threadIdx.x;
  int c = tid >> 4, n = tid & 15;
  float A_dn = -__expf(Alog[(d0 + c)*16 + n]);
  __shared__ float2 sdd[16][SEG+2];   // (dlt, u)
  __shared__ float2 sBC[SEG][17];     // (B_n, C_n)
  __shared__ float  sy [16][SEG+1];
  __shared__ float  sD[16];
  if (tid < 16) sD[tid] = Dp[d0 + tid];
  int t0 = s*SEG;
  int nt = L_WIN - t0; if (nt > SEG) nt = SEG;
  size_t base_m = (size_t)b*L_WIN + t0;
  // inline hstart: fold Pq[0..s-1] in increasing order (identical to old combine)
  float h = 0.f;
  {
    const float2* pqb = Pq + (((size_t)b*NSEG) << 14) + d0*16 + tid;
    for (int k = 0; k < s; ++k){
      float2 pq = pqb[(size_t)k << 14];
      h = fmaf(pq.x, h, pq.y);
    }
  }
  for (int i2 = tid; i2 < 16*SEG; i2 += 256){
    int tt = i2 >> 4, dd = i2 & 15;
    float dlt = 0.f, uu = 0.f, Bv = 0.f, Cv = 0.f;
    if (tt < nt){
      size_t m = base_m + tt;
      dlt = (float)delta16[m*DI + d0 + dd];
      uu  = (float)u16[m*DI + d0 + dd];
      Bv  = xdbl[m*48 + 16 + dd];
      Cv  = xdbl[m*48 + 32 + dd];
    }
    sdd[dd][tt] = make_float2(dlt, uu);
    sBC[tt][dd] = make_float2(Bv, Cv);
  }
  __syncthreads();
  #pragma unroll 8
  for (int t = 0; t < SEG; ++t){
    float2 dd2 = sdd[c][t];
    float dA = __expf(dd2.x * A_dn);
    float2 bc = sBC[t][n];
    h = fmaf(dA, h, dd2.x * dd2.y * bc.x);
    float pp = h * bc.y;
    pp = dpp_add<0xB1>(pp);    // xor1
    pp = dpp_add<0x4E>(pp);    // xor2
    pp = dpp_add<0x141>(pp);   // row_half_mirror
    pp = dpp_add<0x128>(pp);   // row_ror:8
    if (n == 0) sy[c][t] = pp;
  }
  __syncthreads();
  for (int i2 = tid; i2 < 16*nt; i2 += 256){
    int tt = i2 >> 4, dd = i2 & 15;
    size_t m = base_m + tt;
    float uv = sdd[dd][tt].y;
    float zv = (float)xz16[m*2048 + 1024 + d0 + dd];
    float yv = (sy[dd][tt] + uv * sD[dd]) * (zv * sigmoidf_(zv));
    y16[m*DI + d0 + dd] = (__bf16)yv;
  }
}

// ---------------- overlap-add fold + passthrough ----------------
__global__ __launch_bounds__(256) void fold_kernel(const float* __restrict__ x, const float* __restrict__ r,
                                                   float* __restrict__ out){
  int i = blockIdx.x*256 + threadIdx.x;
  int b = i >> 17;
  int t = i & (TLEN - 1);
  float acc = x[i];
  int l1 = t >> 7;
  int j  = t & 127;
  if (l1 < L_WIN) acc += r[((size_t)b*L_WIN + l1)*DIMC + j] * ((float)j * (1.f/127.f));
  if (l1 >= 1)    acc += r[((size_t)b*L_WIN + l1 - 1)*DIMC + j + 128] * ((float)(127 - j) * (1.f/127.f));
  out[i] = acc;
}

extern "C" void kernel_launch(void* const* d_in, const int* in_sizes, int n_in,
                              void* d_out, int out_size, void* d_ws, size_t ws_size,
                              hipStream_t stream)
{
  (void)in_sizes; (void)n_in; (void)out_size; (void)ws_size;
  const float* x      = (const float*)d_in[0];
  const float* in_w   = (const float*)d_in[1];
  const float* conv_w = (const float*)d_in[2];
  const float* conv_b = (const float*)d_in[3];
  const float* xp_w   = (const float*)d_in[4];
  const float* dt_w   = (const float*)d_in[5];
  const float* dt_b   = (const float*)d_in[6];
  const float* A_log  = (const float*)d_in[7];
  const float* Dp     = (const float*)d_in[8];
  const float* out_w  = (const float*)d_in[9];
  const float* norm_w = (const float*)d_in[10];
  float* out = (float*)d_out;

  // workspace layout (~66 MB; ws is 256 MiB)
  char* p = (char*)d_ws;
  auto alloc = [&](size_t bytes)->void*{ void* r = (void*)p; p += (bytes + 255) & ~(size_t)255; return r; };
  float*  res    = (float*) alloc((size_t)M_PAD*DIMC*4);        // 4 MB
  __bf16* hn16   = (__bf16*)alloc((size_t)M_PAD*DIMC*2);        // 2 MB
  __bf16* xz16   = (__bf16*)alloc((size_t)M_PAD*2048*2);        // 16 MB
  __bf16* u16    = (__bf16*)alloc((size_t)M_PAD*DI*2);          // 8 MB
  float*  xdbl   = (float*) alloc((size_t)M_PAD*48*4);          // 0.75 MB
  __bf16* delta16= (__bf16*)alloc((size_t)M_PAD*DI*2);          // 8 MB
  __bf16* y16    = (__bf16*)alloc((size_t)M_PAD*DI*2);          // 8 MB
  float2* Pq     = (float2*)alloc((size_t)4*NSEG*16384*8);      // 16 MB
  __bf16* w_in16 = (__bf16*)alloc((size_t)2*2048*256*2);        // 2 MB
  __bf16* w_xp16 = (__bf16*)alloc((size_t)2*48*1024*2);         // 0.19 MB
  __bf16* w_out16= (__bf16*)alloc((size_t)2*256*1024*2);        // 1 MB

  init_kernel<<<M_PAD + 512, 256, 0, stream>>>(x, res,
                                               in_w, w_in16, 2*2048*256,
                                               xp_w, w_xp16, 2*48*1024,
                                               out_w, w_out16, 2*256*1024);

  for (int i = 0; i < 2; ++i){
    rms_kernel<<<M_PAD, 256, 0, stream>>>(res, hn16, norm_w + i*256);
    gemm_tiled_kernel<4, 4, __bf16><<<dim3(32, 16), 256, 0, stream>>>(hn16, w_in16 + (size_t)i*524288, xz16, nullptr, 256, 2048);
    conv_xproj_dt_kernel<<<M_PAD/16, 256, 0, stream>>>(xz16, conv_w + i*4096, conv_b + i*1024,
                                                       w_xp16 + (size_t)i*49152, dt_w + i*16384, dt_b + i*1024,
                                                       u16, xdbl, delta16);
    scan_part1_kernel<<<8192, 256, 0, stream>>>(u16, delta16, xdbl, A_log + i*16384, Pq);
    scan_part2_kernel<<<8192, 256, 0, stream>>>(u16, delta16, xdbl, xz16, A_log + i*16384, Dp + i*1024,
                                                Pq, y16);
    gemm_tiled_kernel<2, 2, float><<<dim3(64, 4), 256, 0, stream>>>(y16, w_out16 + (size_t)i*262144, res, res, 1024, 256);
  }
  fold_kernel<<<TLEN*4/256, 256, 0, stream>>>(x, res, out);
}

// Round 15
// 338.054 us; speedup vs baseline: 1.1596x; 1.1596x over previous
//
#include <hip/hip_runtime.h>
#include <cmath>

// ---- problem constants ----
#define DIMC   256
#define L_WIN  1023        // (131072-256)/128 + 1
#define M_VALID 4092       // 4*1023 tokens
#define M_PAD  4096
#define DI     1024        // D_INNER
#define TLEN   131072
#define SEG    32          // scan segment length
#define NSEG   32          // 32*32 = 1024 >= 1023

typedef __bf16 bf16x8 __attribute__((ext_vector_type(8)));
typedef __bf16 bf16x4 __attribute__((ext_vector_type(4)));
typedef float  f32x4  __attribute__((ext_vector_type(4)));

__device__ __forceinline__ float sigmoidf_(float x){ return 1.f/(1.f + __expf(-x)); }
__device__ __forceinline__ float softplusf_(float v){ return fmaxf(v,0.f) + log1pf(__expf(-fabsf(v))); }

// DPP rotate-add: pure-VALU cross-lane sum step (no LDS traffic)
template<int CTRL>
__device__ __forceinline__ float dpp_add(float x){
  int v = __builtin_amdgcn_update_dpp(0, __builtin_bit_cast(int, x), CTRL, 0xF, 0xF, true);
  return x + __builtin_bit_cast(float, v);
}

// ---------------- init: frame (blocks 0..4095) + weight bf16 convert (blocks 4096+) ----------------
__global__ __launch_bounds__(256) void init_kernel(const float* __restrict__ x, float* __restrict__ res,
    const float* __restrict__ a, __bf16* __restrict__ da, int na,
    const float* __restrict__ b, __bf16* __restrict__ db, int nb,
    const float* __restrict__ c, __bf16* __restrict__ dc, int nc)
{
  if (blockIdx.x < M_PAD){
    int m = blockIdx.x, j = threadIdx.x;
    float v = 0.f;
    if (m < M_VALID){
      int bb = m / L_WIN, l = m - bb*L_WIN;
      v = x[(size_t)bb*TLEN + l*128 + j];
    }
    res[(size_t)m*DIMC + j] = v;
    return;
  }
  int nblk = gridDim.x - M_PAD;
  int stride = nblk*256;
  int base = (blockIdx.x - M_PAD)*256 + threadIdx.x;
  for (int i = base; i < na; i += stride) da[i] = (__bf16)a[i];
  for (int i = base; i < nb; i += stride) db[i] = (__bf16)b[i];
  for (int i = base; i < nc; i += stride) dc[i] = (__bf16)c[i];
}

// ---------------- rmsnorm row of 256 -> bf16 ----------------
__global__ __launch_bounds__(256) void rms_kernel(const float* __restrict__ src, __bf16* __restrict__ dst,
                                                  const float* __restrict__ w){
  int m = blockIdx.x, j = threadIdx.x;
  float v = (m < M_VALID) ? src[(size_t)m*DIMC + j] : 0.f;
  float s = v*v;
  #pragma unroll
  for (int off = 32; off; off >>= 1) s += __shfl_down(s, off);
  __shared__ float ls[4];
  if ((threadIdx.x & 63) == 0) ls[threadIdx.x >> 6] = s;
  __syncthreads();
  float tot = ls[0] + ls[1] + ls[2] + ls[3];
  float scale = rsqrtf(tot * (1.f/DIMC) + 1e-5f);
  dst[(size_t)m*DIMC + j] = (__bf16)(v * scale * w[j]);
}

// ======== LDS-tiled bf16 MFMA GEMM: C[M x N] = A[M x K] * B[N x K]^T (+addsrc) ========
// NOTE: C/addsrc NOT __restrict__ — out_proj call is in-place (C==addsrc).
template<int WM, int WN, typename OutT>
__global__ __launch_bounds__(256) void gemm_tiled_kernel(const __bf16* __restrict__ A, const __bf16* __restrict__ B,
    OutT* C, const float* addsrc, int K, int ldc)
{
  constexpr int BM  = 32*WM;
  constexpr int BN  = 32*WN;
  constexpr int LDK = 72;
  __shared__ __bf16 As[BM*LDK];
  __shared__ __bf16 Bs[BN*LDK];
  int tid  = threadIdx.x;
  int lane = tid & 63, wv = tid >> 6;
  int row  = lane & 15, kq = lane >> 4;
  int m0 = blockIdx.x*BM, n0 = blockIdx.y*BN;
  int wmo = (wv >> 1)*(16*WM);
  int wno = (wv &  1)*(16*WN);
  f32x4 acc[WM][WN] = {};
  for (int kt = 0; kt < K; kt += 64){
    __syncthreads();
    #pragma unroll
    for (int r = 0; r < BM/32; ++r){
      int seg = r*256 + tid;
      int rw = seg >> 3, sb = seg & 7;
      *(bf16x8*)(As + rw*LDK + sb*8) = *(const bf16x8*)(A + (size_t)(m0 + rw)*K + kt + sb*8);
    }
    #pragma unroll
    for (int r = 0; r < BN/32; ++r){
      int seg = r*256 + tid;
      int rw = seg >> 3, sb = seg & 7;
      *(bf16x8*)(Bs + rw*LDK + sb*8) = *(const bf16x8*)(B + (size_t)(n0 + rw)*K + kt + sb*8);
    }
    __syncthreads();
    #pragma unroll
    for (int ks = 0; ks < 2; ++ks){
      bf16x8 af[WM], bfr[WN];
      #pragma unroll
      for (int i = 0; i < WM; ++i) af[i]  = *(const bf16x8*)(As + (wmo + i*16 + row)*LDK + ks*32 + kq*8);
      #pragma unroll
      for (int j = 0; j < WN; ++j) bfr[j] = *(const bf16x8*)(Bs + (wno + j*16 + row)*LDK + ks*32 + kq*8);
      #pragma unroll
      for (int i = 0; i < WM; ++i){
        #pragma unroll
        for (int j = 0; j < WN; ++j)
          acc[i][j] = __builtin_amdgcn_mfma_f32_16x16x32_bf16(af[i], bfr[j], acc[i][j], 0, 0, 0);
      }
    }
  }
  #pragma unroll
  for (int i = 0; i < WM; ++i){
    int cm = m0 + wmo + i*16 + kq*4;
    #pragma unroll
    for (int j = 0; j < WN; ++j){
      int cn = n0 + wno + j*16 + row;
      #pragma unroll
      for (int ii = 0; ii < 4; ++ii){
        size_t idx = (size_t)(cm + ii)*ldc + cn;
        float v = acc[i][j][ii];
        if (addsrc) v += addsrc[idx];
        C[idx] = (OutT)v;
      }
    }
  }
}

// ======== fused conv4+SiLU -> xproj MFMA -> dt_proj+softplus ========
// grid = M_PAD/16 = 256 blocks, 256 thr. Block owns 16 tokens x all 1024 channels.
__global__ __launch_bounds__(256) void conv_xproj_dt_kernel(
  const __bf16* __restrict__ xz16, const float* __restrict__ cw, const float* __restrict__ cb,
  const __bf16* __restrict__ wxp, const float* __restrict__ dtw, const float* __restrict__ dtb,
  __bf16* __restrict__ u16, float* __restrict__ xdbl, __bf16* __restrict__ delta16)
{
  __shared__ __bf16 su[16][1032];   // +8 pad
  __shared__ float  sdt[16][17];
  int tid = threadIdx.x;
  int m0 = blockIdx.x * 16;
  // ---- phase A: causal depthwise conv4 + bias + SiLU ----
  {
    int d = tid * 4;
    float w[4][4], bias[4];
    #pragma unroll
    for (int c = 0; c < 4; ++c){
      #pragma unroll
      for (int j = 0; j < 4; ++j) w[c][j] = cw[(d + c)*4 + j];
      bias[c] = cb[d + c];
    }
    for (int ti = 0; ti < 16; ++ti){
      int m = m0 + ti;
      float acc[4] = {0.f, 0.f, 0.f, 0.f};
      if (m < M_VALID){
        int b = m / L_WIN;
        int l = m - b*L_WIN;
        #pragma unroll
        for (int c = 0; c < 4; ++c) acc[c] = bias[c];
        #pragma unroll
        for (int k = 0; k < 4; ++k){
          if (l >= k){
            bf16x4 xv = *(const bf16x4*)(xz16 + (size_t)(m - k)*2048 + d);
            #pragma unroll
            for (int c = 0; c < 4; ++c) acc[c] = fmaf((float)xv[c], w[c][3-k], acc[c]);
          }
        }
        #pragma unroll
        for (int c = 0; c < 4; ++c) acc[c] = acc[c] * sigmoidf_(acc[c]);
      }
      bf16x4 o;
      #pragma unroll
      for (int c = 0; c < 4; ++c) o[c] = (__bf16)acc[c];
      *(bf16x4*)(u16 + (size_t)m*DI + d) = o;
      *(bf16x4*)(&su[ti][d]) = o;
    }
  }
  __syncthreads();
  // ---- phase B: xproj, 16 tokens x 48 outputs, K=1024 ----
  {
    int lane = tid & 63, wv = tid >> 6;
    if (wv < 3){
      int row = lane & 15, kq = lane >> 4;
      f32x4 acc = {0.f, 0.f, 0.f, 0.f};
      const __bf16* Bp = wxp + (size_t)(wv*16 + row)*1024 + kq*8;
      for (int k = 0; k < 1024; k += 32){
        bf16x8 a  = *(const bf16x8*)(&su[row][k + kq*8]);
        bf16x8 bb = *(const bf16x8*)(Bp + k);
        acc = __builtin_amdgcn_mfma_f32_16x16x32_bf16(a, bb, acc, 0, 0, 0);
      }
      #pragma unroll
      for (int i = 0; i < 4; ++i){
        int tok = kq*4 + i;
        xdbl[(size_t)(m0 + tok)*48 + wv*16 + row] = acc[i];
        if (wv == 0) sdt[tok][row] = acc[i];
      }
    }
  }
  __syncthreads();
  // ---- phase C: dt_proj (K=16) + softplus -> delta16 ----
  {
    int d0 = tid * 4;
    float w[4][16], bias[4];
    #pragma unroll
    for (int c = 0; c < 4; ++c){
      #pragma unroll
      for (int q = 0; q < 16; ++q) w[c][q] = dtw[(d0 + c)*16 + q];
      bias[c] = dtb[d0 + c];
    }
    for (int t = 0; t < 16; ++t){
      float acc[4] = {bias[0], bias[1], bias[2], bias[3]};
      #pragma unroll
      for (int r = 0; r < 16; ++r){
        float dv = sdt[t][r];
        #pragma unroll
        for (int c = 0; c < 4; ++c) acc[c] = fmaf(dv, w[c][r], acc[c]);
      }
      bf16x4 o;
      #pragma unroll
      for (int c = 0; c < 4; ++c) o[c] = (__bf16)softplusf_(acc[c]);
      *(bf16x4*)(delta16 + (size_t)(m0 + t)*DI + d0) = o;
    }
  }
}

// ================= chunked two-phase selective scan =================
__global__ __launch_bounds__(256) void scan_part1_kernel(
  const __bf16* __restrict__ u16, const __bf16* __restrict__ delta16,
  const float* __restrict__ xdbl, const float* __restrict__ Alog, float2* __restrict__ Pq)
{
  int bid = blockIdx.x;
  int s = bid & 31, dtile = (bid >> 5) & 63, b = bid >> 11;
  int d0 = dtile << 4;
  int tid = threadIdx.x;
  int c = tid >> 4, n = tid & 15;
  float A_dn = -__expf(Alog[(d0 + c)*16 + n]);
  __shared__ float2 sdd[16][SEG+2];   // (dlt, dlt*u)
  __shared__ float  sB [SEG][17];
  int t0 = s*SEG;
  int nt = L_WIN - t0; if (nt > SEG) nt = SEG;
  size_t base_m = (size_t)b*L_WIN + t0;
  for (int i2 = tid; i2 < 16*SEG; i2 += 256){
    int tt = i2 >> 4, dd = i2 & 15;
    float dlt = 0.f, du = 0.f, Bv = 0.f;
    if (tt < nt){
      size_t m = base_m + tt;
      dlt = (float)delta16[m*DI + d0 + dd];
      du  = dlt * (float)u16[m*DI + d0 + dd];
      Bv  = xdbl[m*48 + 16 + dd];
    }
    sdd[dd][tt] = make_float2(dlt, du);
    sB[tt][dd]  = Bv;
  }
  __syncthreads();
  float h = 0.f, P = 1.f;
  #pragma unroll 8
  for (int t = 0; t < SEG; ++t){
    float2 dd2 = sdd[c][t];
    float dA = __expf(dd2.x * A_dn);
    h = fmaf(dA, h, dd2.y * sB[t][n]);
    P *= dA;
  }
  Pq[(((size_t)b*NSEG + s) << 14) + d0*16 + tid] = make_float2(P, h);
}

__global__ __launch_bounds__(256) void scan_combine_kernel(const float2* __restrict__ Pq,
                                                           float* __restrict__ hstart)
{
  int idx = blockIdx.x*256 + threadIdx.x;
  int b = idx >> 14;
  int dn = idx & 16383;
  float hs = 0.f;
  #pragma unroll
  for (int s = 0; s < NSEG; ++s){
    size_t o = (((size_t)b*NSEG + s) << 14) + dn;
    hstart[o] = hs;
    float2 pq = Pq[o];
    hs = fmaf(pq.x, hs, pq.y);
  }
}

__global__ __launch_bounds__(256) void scan_part2_kernel(
  const __bf16* __restrict__ u16, const __bf16* __restrict__ delta16,
  const float* __restrict__ xdbl, const __bf16* __restrict__ xz16,
  const float* __restrict__ Alog, const float* __restrict__ Dp,
  const float* __restrict__ hstart, __bf16* __restrict__ y16)
{
  int bid = blockIdx.x;
  int s = bid & 31, dtile = (bid >> 5) & 63, b = bid >> 11;
  int d0 = dtile << 4;
  int tid = threadIdx.x;
  int c = tid >> 4, n = tid & 15;
  float A_dn = -__expf(Alog[(d0 + c)*16 + n]);
  __shared__ float2 sdd[16][SEG+2];   // (dlt, u)
  __shared__ float2 sBC[SEG][17];     // (B_n, C_n)
  __shared__ float  sy [16][SEG+1];
  __shared__ float  sD[16];
  if (tid < 16) sD[tid] = Dp[d0 + tid];
  int t0 = s*SEG;
  int nt = L_WIN - t0; if (nt > SEG) nt = SEG;
  size_t base_m = (size_t)b*L_WIN + t0;
  for (int i2 = tid; i2 < 16*SEG; i2 += 256){
    int tt = i2 >> 4, dd = i2 & 15;
    float dlt = 0.f, uu = 0.f, Bv = 0.f, Cv = 0.f;
    if (tt < nt){
      size_t m = base_m + tt;
      dlt = (float)delta16[m*DI + d0 + dd];
      uu  = (float)u16[m*DI + d0 + dd];
      Bv  = xdbl[m*48 + 16 + dd];
      Cv  = xdbl[m*48 + 32 + dd];
    }
    sdd[dd][tt] = make_float2(dlt, uu);
    sBC[tt][dd] = make_float2(Bv, Cv);
  }
  float h = hstart[(((size_t)b*NSEG + s) << 14) + d0*16 + tid];
  __syncthreads();
  #pragma unroll 8
  for (int t = 0; t < SEG; ++t){
    float2 dd2 = sdd[c][t];
    float dA = __expf(dd2.x * A_dn);
    float2 bc = sBC[t][n];
    h = fmaf(dA, h, dd2.x * dd2.y * bc.x);
    float pp = h * bc.y;
    pp = dpp_add<0xB1>(pp);    // xor1
    pp = dpp_add<0x4E>(pp);    // xor2
    pp = dpp_add<0x141>(pp);   // row_half_mirror
    pp = dpp_add<0x128>(pp);   // row_ror:8
    if (n == 0) sy[c][t] = pp;
  }
  __syncthreads();
  for (int i2 = tid; i2 < 16*nt; i2 += 256){
    int tt = i2 >> 4, dd = i2 & 15;
    size_t m = base_m + tt;
    float uv = sdd[dd][tt].y;
    float zv = (float)xz16[m*2048 + 1024 + d0 + dd];
    float yv = (sy[dd][tt] + uv * sD[dd]) * (zv * sigmoidf_(zv));
    y16[m*DI + d0 + dd] = (__bf16)yv;
  }
}

// ---------------- overlap-add fold + passthrough ----------------
__global__ __launch_bounds__(256) void fold_kernel(const float* __restrict__ x, const float* __restrict__ r,
                                                   float* __restrict__ out){
  int i = blockIdx.x*256 + threadIdx.x;
  int b = i >> 17;
  int t = i & (TLEN - 1);
  float acc = x[i];
  int l1 = t >> 7;
  int j  = t & 127;
  if (l1 < L_WIN) acc += r[((size_t)b*L_WIN + l1)*DIMC + j] * ((float)j * (1.f/127.f));
  if (l1 >= 1)    acc += r[((size_t)b*L_WIN + l1 - 1)*DIMC + j + 128] * ((float)(127 - j) * (1.f/127.f));
  out[i] = acc;
}

extern "C" void kernel_launch(void* const* d_in, const int* in_sizes, int n_in,
                              void* d_out, int out_size, void* d_ws, size_t ws_size,
                              hipStream_t stream)
{
  (void)in_sizes; (void)n_in; (void)out_size; (void)ws_size;
  const float* x      = (const float*)d_in[0];
  const float* in_w   = (const float*)d_in[1];
  const float* conv_w = (const float*)d_in[2];
  const float* conv_b = (const float*)d_in[3];
  const float* xp_w   = (const float*)d_in[4];
  const float* dt_w   = (const float*)d_in[5];
  const float* dt_b   = (const float*)d_in[6];
  const float* A_log  = (const float*)d_in[7];
  const float* Dp     = (const float*)d_in[8];
  const float* out_w  = (const float*)d_in[9];
  const float* norm_w = (const float*)d_in[10];
  float* out = (float*)d_out;

  // workspace layout (~74 MB; ws is 256 MiB)
  char* p = (char*)d_ws;
  auto alloc = [&](size_t bytes)->void*{ void* r = (void*)p; p += (bytes + 255) & ~(size_t)255; return r; };
  float*  res    = (float*) alloc((size_t)M_PAD*DIMC*4);        // 4 MB
  __bf16* hn16   = (__bf16*)alloc((size_t)M_PAD*DIMC*2);        // 2 MB
  __bf16* xz16   = (__bf16*)alloc((size_t)M_PAD*2048*2);        // 16 MB
  __bf16* u16    = (__bf16*)alloc((size_t)M_PAD*DI*2);          // 8 MB
  float*  xdbl   = (float*) alloc((size_t)M_PAD*48*4);          // 0.75 MB
  __bf16* delta16= (__bf16*)alloc((size_t)M_PAD*DI*2);          // 8 MB
  __bf16* y16    = (__bf16*)alloc((size_t)M_PAD*DI*2);          // 8 MB
  float2* Pq     = (float2*)alloc((size_t)4*NSEG*16384*8);      // 16 MB
  float*  hstart = (float*) alloc((size_t)4*NSEG*16384*4);      // 8 MB
  __bf16* w_in16 = (__bf16*)alloc((size_t)2*2048*256*2);        // 2 MB
  __bf16* w_xp16 = (__bf16*)alloc((size_t)2*48*1024*2);         // 0.19 MB
  __bf16* w_out16= (__bf16*)alloc((size_t)2*256*1024*2);        // 1 MB

  init_kernel<<<M_PAD + 512, 256, 0, stream>>>(x, res,
                                               in_w, w_in16, 2*2048*256,
                                               xp_w, w_xp16, 2*48*1024,
                                               out_w, w_out16, 2*256*1024);

  for (int i = 0; i < 2; ++i){
    rms_kernel<<<M_PAD, 256, 0, stream>>>(res, hn16, norm_w + i*256);
    gemm_tiled_kernel<4, 4, __bf16><<<dim3(32, 16), 256, 0, stream>>>(hn16, w_in16 + (size_t)i*524288, xz16, nullptr, 256, 2048);
    conv_xproj_dt_kernel<<<M_PAD/16, 256, 0, stream>>>(xz16, conv_w + i*4096, conv_b + i*1024,
                                                       w_xp16 + (size_t)i*49152, dt_w + i*16384, dt_b + i*1024,
                                                       u16, xdbl, delta16);
    scan_part1_kernel<<<8192, 256, 0, stream>>>(u16, delta16, xdbl, A_log + i*16384, Pq);
    scan_combine_kernel<<<256, 256, 0, stream>>>(Pq, hstart);
    scan_part2_kernel<<<8192, 256, 0, stream>>>(u16, delta16, xdbl, xz16, A_log + i*16384, Dp + i*1024,
                                                hstart, y16);
    gemm_tiled_kernel<2, 2, float><<<dim3(64, 4), 256, 0, stream>>>(y16, w_out16 + (size_t)i*262144, res, res, 1024, 256);
  }
  fold_kernel<<<TLEN*4/256, 256, 0, stream>>>(x, res, out);
}

// Round 16
// 332.902 us; speedup vs baseline: 1.1776x; 1.0155x over previous
//
#include <hip/hip_runtime.h>
#include <cmath>

// ---- problem constants ----
#define DIMC   256
#define L_WIN  1023        // (131072-256)/128 + 1
#define M_VALID 4092       // 4*1023 tokens
#define M_PAD  4096
#define DI     1024        // D_INNER
#define TLEN   131072
#define SEG    32          // scan segment length
#define NSEG   32          // 32*32 = 1024 >= 1023

typedef __bf16 bf16x8 __attribute__((ext_vector_type(8)));
typedef __bf16 bf16x4 __attribute__((ext_vector_type(4)));
typedef float  f32x4  __attribute__((ext_vector_type(4)));

__device__ __forceinline__ float sigmoidf_(float x){ return 1.f/(1.f + __expf(-x)); }
__device__ __forceinline__ float softplusf_(float v){ return fmaxf(v,0.f) + log1pf(__expf(-fabsf(v))); }

// DPP rotate-add: pure-VALU cross-lane sum step (no LDS traffic)
template<int CTRL>
__device__ __forceinline__ float dpp_add(float x){
  int v = __builtin_amdgcn_update_dpp(0, __builtin_bit_cast(int, x), CTRL, 0xF, 0xF, true);
  return x + __builtin_bit_cast(float, v);
}

// ---------------- init: frame (blocks 0..4095) + weight bf16 convert (blocks 4096+) ----------------
__global__ __launch_bounds__(256) void init_kernel(const float* __restrict__ x, float* __restrict__ res,
    const float* __restrict__ a, __bf16* __restrict__ da, int na,
    const float* __restrict__ b, __bf16* __restrict__ db, int nb,
    const float* __restrict__ c, __bf16* __restrict__ dc, int nc)
{
  if (blockIdx.x < M_PAD){
    int m = blockIdx.x, j = threadIdx.x;
    float v = 0.f;
    if (m < M_VALID){
      int bb = m / L_WIN, l = m - bb*L_WIN;
      v = x[(size_t)bb*TLEN + l*128 + j];
    }
    res[(size_t)m*DIMC + j] = v;
    return;
  }
  int nblk = gridDim.x - M_PAD;
  int stride = nblk*256;
  int base = (blockIdx.x - M_PAD)*256 + threadIdx.x;
  for (int i = base; i < na; i += stride) da[i] = (__bf16)a[i];
  for (int i = base; i < nb; i += stride) db[i] = (__bf16)b[i];
  for (int i = base; i < nc; i += stride) dc[i] = (__bf16)c[i];
}

// ---------------- rmsnorm row of 256 -> bf16 ----------------
__global__ __launch_bounds__(256) void rms_kernel(const float* __restrict__ src, __bf16* __restrict__ dst,
                                                  const float* __restrict__ w){
  int m = blockIdx.x, j = threadIdx.x;
  float v = (m < M_VALID) ? src[(size_t)m*DIMC + j] : 0.f;
  float s = v*v;
  #pragma unroll
  for (int off = 32; off; off >>= 1) s += __shfl_down(s, off);
  __shared__ float ls[4];
  if ((threadIdx.x & 63) == 0) ls[threadIdx.x >> 6] = s;
  __syncthreads();
  float tot = ls[0] + ls[1] + ls[2] + ls[3];
  float scale = rsqrtf(tot * (1.f/DIMC) + 1e-5f);
  dst[(size_t)m*DIMC + j] = (__bf16)(v * scale * w[j]);
}

// ======== LDS-tiled bf16 MFMA GEMM: C[M x N] = A[M x K] * B[N x K]^T (+addsrc) ========
// NOTE: C/addsrc NOT __restrict__ — out_proj call is in-place (C==addsrc).
template<int WM, int WN, typename OutT>
__global__ __launch_bounds__(256) void gemm_tiled_kernel(const __bf16* __restrict__ A, const __bf16* __restrict__ B,
    OutT* C, const float* addsrc, int K, int ldc)
{
  constexpr int BM  = 32*WM;
  constexpr int BN  = 32*WN;
  constexpr int LDK = 72;
  __shared__ __bf16 As[BM*LDK];
  __shared__ __bf16 Bs[BN*LDK];
  int tid  = threadIdx.x;
  int lane = tid & 63, wv = tid >> 6;
  int row  = lane & 15, kq = lane >> 4;
  int m0 = blockIdx.x*BM, n0 = blockIdx.y*BN;
  int wmo = (wv >> 1)*(16*WM);
  int wno = (wv &  1)*(16*WN);
  f32x4 acc[WM][WN] = {};
  for (int kt = 0; kt < K; kt += 64){
    __syncthreads();
    #pragma unroll
    for (int r = 0; r < BM/32; ++r){
      int seg = r*256 + tid;
      int rw = seg >> 3, sb = seg & 7;
      *(bf16x8*)(As + rw*LDK + sb*8) = *(const bf16x8*)(A + (size_t)(m0 + rw)*K + kt + sb*8);
    }
    #pragma unroll
    for (int r = 0; r < BN/32; ++r){
      int seg = r*256 + tid;
      int rw = seg >> 3, sb = seg & 7;
      *(bf16x8*)(Bs + rw*LDK + sb*8) = *(const bf16x8*)(B + (size_t)(n0 + rw)*K + kt + sb*8);
    }
    __syncthreads();
    #pragma unroll
    for (int ks = 0; ks < 2; ++ks){
      bf16x8 af[WM], bfr[WN];
      #pragma unroll
      for (int i = 0; i < WM; ++i) af[i]  = *(const bf16x8*)(As + (wmo + i*16 + row)*LDK + ks*32 + kq*8);
      #pragma unroll
      for (int j = 0; j < WN; ++j) bfr[j] = *(const bf16x8*)(Bs + (wno + j*16 + row)*LDK + ks*32 + kq*8);
      #pragma unroll
      for (int i = 0; i < WM; ++i){
        #pragma unroll
        for (int j = 0; j < WN; ++j)
          acc[i][j] = __builtin_amdgcn_mfma_f32_16x16x32_bf16(af[i], bfr[j], acc[i][j], 0, 0, 0);
      }
    }
  }
  #pragma unroll
  for (int i = 0; i < WM; ++i){
    int cm = m0 + wmo + i*16 + kq*4;
    #pragma unroll
    for (int j = 0; j < WN; ++j){
      int cn = n0 + wno + j*16 + row;
      #pragma unroll
      for (int ii = 0; ii < 4; ++ii){
        size_t idx = (size_t)(cm + ii)*ldc + cn;
        float v = acc[i][j][ii];
        if (addsrc) v += addsrc[idx];
        C[idx] = (OutT)v;
      }
    }
  }
}

// ======== fused conv4+SiLU -> xproj MFMA (K-split, 4 waves) -> dt_proj+softplus ========
// grid = M_PAD/16 = 256 blocks, 256 thr. Block owns 16 tokens x all 1024 channels.
// r16: phase A rolling-register conv (19 loads/thread vs 64); phase B K-split across
// all 4 waves (4x shorter MFMA chains, no idle wave), partial-sum reduce via LDS.
__global__ __launch_bounds__(256) void conv_xproj_dt_kernel(
  const __bf16* __restrict__ xz16, const float* __restrict__ cw, const float* __restrict__ cb,
  const __bf16* __restrict__ wxp, const float* __restrict__ dtw, const float* __restrict__ dtb,
  __bf16* __restrict__ u16, float* __restrict__ xdbl, __bf16* __restrict__ delta16)
{
  __shared__ __bf16 su[16][1032];   // +8 pad
  __shared__ float  sdt[16][17];
  __shared__ f32x4  spart[4][3][64];  // [kwave][tile][lane] partial xproj sums (12 KB)
  int tid = threadIdx.x;
  int m0 = blockIdx.x * 16;
  // ---- phase A: causal depthwise conv4 + bias + SiLU (rolling 4-row register window) ----
  {
    int d = tid * 4;
    float w[4][4], bias[4];
    #pragma unroll
    for (int c = 0; c < 4; ++c){
      #pragma unroll
      for (int j = 0; j < 4; ++j) w[c][j] = cw[(d + c)*4 + j];
      bias[c] = cb[d + c];
    }
    bf16x4 zero4; zero4[0] = (__bf16)0.f; zero4[1] = (__bf16)0.f; zero4[2] = (__bf16)0.f; zero4[3] = (__bf16)0.f;
    bf16x4 rm3 = (m0 >= 3) ? *(const bf16x4*)(xz16 + (size_t)(m0-3)*2048 + d) : zero4;
    bf16x4 rm2 = (m0 >= 2) ? *(const bf16x4*)(xz16 + (size_t)(m0-2)*2048 + d) : zero4;
    bf16x4 rm1 = (m0 >= 1) ? *(const bf16x4*)(xz16 + (size_t)(m0-1)*2048 + d) : zero4;
    for (int ti = 0; ti < 16; ++ti){
      int m = m0 + ti;
      bf16x4 cur = *(const bf16x4*)(xz16 + (size_t)m*2048 + d);  // pad rows are zeros
      float acc[4] = {0.f, 0.f, 0.f, 0.f};
      if (m < M_VALID){
        int b = m / L_WIN;
        int l = m - b*L_WIN;
        #pragma unroll
        for (int c = 0; c < 4; ++c) acc[c] = fmaf((float)cur[c], w[c][3], bias[c]);
        if (l >= 1){
          #pragma unroll
          for (int c = 0; c < 4; ++c) acc[c] = fmaf((float)rm1[c], w[c][2], acc[c]);
        }
        if (l >= 2){
          #pragma unroll
          for (int c = 0; c < 4; ++c) acc[c] = fmaf((float)rm2[c], w[c][1], acc[c]);
        }
        if (l >= 3){
          #pragma unroll
          for (int c = 0; c < 4; ++c) acc[c] = fmaf((float)rm3[c], w[c][0], acc[c]);
        }
        #pragma unroll
        for (int c = 0; c < 4; ++c) acc[c] = acc[c] * sigmoidf_(acc[c]);
      }
      bf16x4 o;
      #pragma unroll
      for (int c = 0; c < 4; ++c) o[c] = (__bf16)acc[c];
      *(bf16x4*)(u16 + (size_t)m*DI + d) = o;
      *(bf16x4*)(&su[ti][d]) = o;
      rm3 = rm2; rm2 = rm1; rm1 = cur;
    }
  }
  __syncthreads();
  // ---- phase B: xproj, 16 tokens x 48 outputs, K=1024 split across 4 waves ----
  {
    int lane = tid & 63, wv = tid >> 6;
    int row = lane & 15, kq = lane >> 4;
    int kbase = wv * 256;
    f32x4 acc0 = {0,0,0,0}, acc1 = {0,0,0,0}, acc2 = {0,0,0,0};
    const __bf16* B0 = wxp + (size_t)(row)*1024      + kbase + kq*8;
    const __bf16* B1 = wxp + (size_t)(16 + row)*1024 + kbase + kq*8;
    const __bf16* B2 = wxp + (size_t)(32 + row)*1024 + kbase + kq*8;
    #pragma unroll
    for (int k = 0; k < 256; k += 32){
      bf16x8 a = *(const bf16x8*)(&su[row][kbase + k + kq*8]);
      acc0 = __builtin_amdgcn_mfma_f32_16x16x32_bf16(a, *(const bf16x8*)(B0 + k), acc0, 0, 0, 0);
      acc1 = __builtin_amdgcn_mfma_f32_16x16x32_bf16(a, *(const bf16x8*)(B1 + k), acc1, 0, 0, 0);
      acc2 = __builtin_amdgcn_mfma_f32_16x16x32_bf16(a, *(const bf16x8*)(B2 + k), acc2, 0, 0, 0);
    }
    spart[wv][0][lane] = acc0;
    spart[wv][1][lane] = acc1;
    spart[wv][2][lane] = acc2;
  }
  __syncthreads();
  // ---- reduce partials, write xdbl + sdt ----
  if (tid < 192){
    int tno = tid >> 6, lane = tid & 63;
    int row = lane & 15, kq = lane >> 4;
    f32x4 sum = spart[0][tno][lane];
    sum += spart[1][tno][lane];
    sum += spart[2][tno][lane];
    sum += spart[3][tno][lane];
    #pragma unroll
    for (int i = 0; i < 4; ++i){
      int tok = kq*4 + i;
      xdbl[(size_t)(m0 + tok)*48 + tno*16 + row] = sum[i];
      if (tno == 0) sdt[tok][row] = sum[i];
    }
  }
  __syncthreads();
  // ---- phase C: dt_proj (K=16) + softplus -> delta16 ----
  {
    int d0 = tid * 4;
    float w[4][16], bias[4];
    #pragma unroll
    for (int c = 0; c < 4; ++c){
      #pragma unroll
      for (int q = 0; q < 16; ++q) w[c][q] = dtw[(d0 + c)*16 + q];
      bias[c] = dtb[d0 + c];
    }
    for (int t = 0; t < 16; ++t){
      float acc[4] = {bias[0], bias[1], bias[2], bias[3]};
      #pragma unroll
      for (int r = 0; r < 16; ++r){
        float dv = sdt[t][r];
        #pragma unroll
        for (int c = 0; c < 4; ++c) acc[c] = fmaf(dv, w[c][r], acc[c]);
      }
      bf16x4 o;
      #pragma unroll
      for (int c = 0; c < 4; ++c) o[c] = (__bf16)softplusf_(acc[c]);
      *(bf16x4*)(delta16 + (size_t)(m0 + t)*DI + d0) = o;
    }
  }
}

// ================= chunked two-phase selective scan =================
__global__ __launch_bounds__(256) void scan_part1_kernel(
  const __bf16* __restrict__ u16, const __bf16* __restrict__ delta16,
  const float* __restrict__ xdbl, const float* __restrict__ Alog, float2* __restrict__ Pq)
{
  int bid = blockIdx.x;
  int s = bid & 31, dtile = (bid >> 5) & 63, b = bid >> 11;
  int d0 = dtile << 4;
  int tid = threadIdx.x;
  int c = tid >> 4, n = tid & 15;
  float A_dn = -__expf(Alog[(d0 + c)*16 + n]);
  __shared__ float2 sdd[16][SEG+2];   // (dlt, dlt*u)
  __shared__ float  sB [SEG][17];
  int t0 = s*SEG;
  int nt = L_WIN - t0; if (nt > SEG) nt = SEG;
  size_t base_m = (size_t)b*L_WIN + t0;
  for (int i2 = tid; i2 < 16*SEG; i2 += 256){
    int tt = i2 >> 4, dd = i2 & 15;
    float dlt = 0.f, du = 0.f, Bv = 0.f;
    if (tt < nt){
      size_t m = base_m + tt;
      dlt = (float)delta16[m*DI + d0 + dd];
      du  = dlt * (float)u16[m*DI + d0 + dd];
      Bv  = xdbl[m*48 + 16 + dd];
    }
    sdd[dd][tt] = make_float2(dlt, du);
    sB[tt][dd]  = Bv;
  }
  __syncthreads();
  float h = 0.f, P = 1.f;
  #pragma unroll 8
  for (int t = 0; t < SEG; ++t){
    float2 dd2 = sdd[c][t];
    float dA = __expf(dd2.x * A_dn);
    h = fmaf(dA, h, dd2.y * sB[t][n]);
    P *= dA;
  }
  Pq[(((size_t)b*NSEG + s) << 14) + d0*16 + tid] = make_float2(P, h);
}

__global__ __launch_bounds__(256) void scan_combine_kernel(const float2* __restrict__ Pq,
                                                           float* __restrict__ hstart)
{
  int idx = blockIdx.x*256 + threadIdx.x;
  int b = idx >> 14;
  int dn = idx & 16383;
  float hs = 0.f;
  #pragma unroll
  for (int s = 0; s < NSEG; ++s){
    size_t o = (((size_t)b*NSEG + s) << 14) + dn;
    hstart[o] = hs;
    float2 pq = Pq[o];
    hs = fmaf(pq.x, hs, pq.y);
  }
}

__global__ __launch_bounds__(256) void scan_part2_kernel(
  const __bf16* __restrict__ u16, const __bf16* __restrict__ delta16,
  const float* __restrict__ xdbl, const __bf16* __restrict__ xz16,
  const float* __restrict__ Alog, const float* __restrict__ Dp,
  const float* __restrict__ hstart, __bf16* __restrict__ y16)
{
  int bid = blockIdx.x;
  int s = bid & 31, dtile = (bid >> 5) & 63, b = bid >> 11;
  int d0 = dtile << 4;
  int tid = threadIdx.x;
  int c = tid >> 4, n = tid & 15;
  float A_dn = -__expf(Alog[(d0 + c)*16 + n]);
  __shared__ float2 sdd[16][SEG+2];   // (dlt, u)
  __shared__ float2 sBC[SEG][17];     // (B_n, C_n)
  __shared__ float  sy [16][SEG+1];
  __shared__ float  sD[16];
  if (tid < 16) sD[tid] = Dp[d0 + tid];
  int t0 = s*SEG;
  int nt = L_WIN - t0; if (nt > SEG) nt = SEG;
  size_t base_m = (size_t)b*L_WIN + t0;
  for (int i2 = tid; i2 < 16*SEG; i2 += 256){
    int tt = i2 >> 4, dd = i2 & 15;
    float dlt = 0.f, uu = 0.f, Bv = 0.f, Cv = 0.f;
    if (tt < nt){
      size_t m = base_m + tt;
      dlt = (float)delta16[m*DI + d0 + dd];
      uu  = (float)u16[m*DI + d0 + dd];
      Bv  = xdbl[m*48 + 16 + dd];
      Cv  = xdbl[m*48 + 32 + dd];
    }
    sdd[dd][tt] = make_float2(dlt, uu);
    sBC[tt][dd] = make_float2(Bv, Cv);
  }
  float h = hstart[(((size_t)b*NSEG + s) << 14) + d0*16 + tid];
  __syncthreads();
  #pragma unroll 8
  for (int t = 0; t < SEG; ++t){
    float2 dd2 = sdd[c][t];
    float dA = __expf(dd2.x * A_dn);
    float2 bc = sBC[t][n];
    h = fmaf(dA, h, dd2.x * dd2.y * bc.x);
    float pp = h * bc.y;
    pp = dpp_add<0xB1>(pp);    // xor1
    pp = dpp_add<0x4E>(pp);    // xor2
    pp = dpp_add<0x141>(pp);   // row_half_mirror
    pp = dpp_add<0x128>(pp);   // row_ror:8
    if (n == 0) sy[c][t] = pp;
  }
  __syncthreads();
  for (int i2 = tid; i2 < 16*nt; i2 += 256){
    int tt = i2 >> 4, dd = i2 & 15;
    size_t m = base_m + tt;
    float uv = sdd[dd][tt].y;
    float zv = (float)xz16[m*2048 + 1024 + d0 + dd];
    float yv = (sy[dd][tt] + uv * sD[dd]) * (zv * sigmoidf_(zv));
    y16[m*DI + d0 + dd] = (__bf16)yv;
  }
}

// ---------------- overlap-add fold + passthrough ----------------
__global__ __launch_bounds__(256) void fold_kernel(const float* __restrict__ x, const float* __restrict__ r,
                                                   float* __restrict__ out){
  int i = blockIdx.x*256 + threadIdx.x;
  int b = i >> 17;
  int t = i & (TLEN - 1);
  float acc = x[i];
  int l1 = t >> 7;
  int j  = t & 127;
  if (l1 < L_WIN) acc += r[((size_t)b*L_WIN + l1)*DIMC + j] * ((float)j * (1.f/127.f));
  if (l1 >= 1)    acc += r[((size_t)b*L_WIN + l1 - 1)*DIMC + j + 128] * ((float)(127 - j) * (1.f/127.f));
  out[i] = acc;
}

extern "C" void kernel_launch(void* const* d_in, const int* in_sizes, int n_in,
                              void* d_out, int out_size, void* d_ws, size_t ws_size,
                              hipStream_t stream)
{
  (void)in_sizes; (void)n_in; (void)out_size; (void)ws_size;
  const float* x      = (const float*)d_in[0];
  const float* in_w   = (const float*)d_in[1];
  const float* conv_w = (const float*)d_in[2];
  const float* conv_b = (const float*)d_in[3];
  const float* xp_w   = (const float*)d_in[4];
  const float* dt_w   = (const float*)d_in[5];
  const float* dt_b   = (const float*)d_in[6];
  const float* A_log  = (const float*)d_in[7];
  const float* Dp     = (const float*)d_in[8];
  const float* out_w  = (const float*)d_in[9];
  const float* norm_w = (const float*)d_in[10];
  float* out = (float*)d_out;

  // workspace layout (~74 MB; ws is 256 MiB)
  char* p = (char*)d_ws;
  auto alloc = [&](size_t bytes)->void*{ void* r = (void*)p; p += (bytes + 255) & ~(size_t)255; return r; };
  float*  res    = (float*) alloc((size_t)M_PAD*DIMC*4);        // 4 MB
  __bf16* hn16   = (__bf16*)alloc((size_t)M_PAD*DIMC*2);        // 2 MB
  __bf16* xz16   = (__bf16*)alloc((size_t)M_PAD*2048*2);        // 16 MB
  __bf16* u16    = (__bf16*)alloc((size_t)M_PAD*DI*2);          // 8 MB
  float*  xdbl   = (float*) alloc((size_t)M_PAD*48*4);          // 0.75 MB
  __bf16* delta16= (__bf16*)alloc((size_t)M_PAD*DI*2);          // 8 MB
  __bf16* y16    = (__bf16*)alloc((size_t)M_PAD*DI*2);          // 8 MB
  float2* Pq     = (float2*)alloc((size_t)4*NSEG*16384*8);      // 16 MB
  float*  hstart = (float*) alloc((size_t)4*NSEG*16384*4);      // 8 MB
  __bf16* w_in16 = (__bf16*)alloc((size_t)2*2048*256*2);        // 2 MB
  __bf16* w_xp16 = (__bf16*)alloc((size_t)2*48*1024*2);         // 0.19 MB
  __bf16* w_out16= (__bf16*)alloc((size_t)2*256*1024*2);        // 1 MB

  init_kernel<<<M_PAD + 512, 256, 0, stream>>>(x, res,
                                               in_w, w_in16, 2*2048*256,
                                               xp_w, w_xp16, 2*48*1024,
                                               out_w, w_out16, 2*256*1024);

  for (int i = 0; i < 2; ++i){
    rms_kernel<<<M_PAD, 256, 0, stream>>>(res, hn16, norm_w + i*256);
    gemm_tiled_kernel<4, 4, __bf16><<<dim3(32, 16), 256, 0, stream>>>(hn16, w_in16 + (size_t)i*524288, xz16, nullptr, 256, 2048);
    conv_xproj_dt_kernel<<<M_PAD/16, 256, 0, stream>>>(xz16, conv_w + i*4096, conv_b + i*1024,
                                                       w_xp16 + (size_t)i*49152, dt_w + i*16384, dt_b + i*1024,
                                                       u16, xdbl, delta16);
    scan_part1_kernel<<<8192, 256, 0, stream>>>(u16, delta16, xdbl, A_log + i*16384, Pq);
    scan_combine_kernel<<<256, 256, 0, stream>>>(Pq, hstart);
    scan_part2_kernel<<<8192, 256, 0, stream>>>(u16, delta16, xdbl, xz16, A_log + i*16384, Dp + i*1024,
                                                hstart, y16);
    gemm_tiled_kernel<2, 2, float><<<dim3(64, 4), 256, 0, stream>>>(y16, w_out16 + (size_t)i*262144, res, res, 1024, 256);
  }
  fold_kernel<<<TLEN*4/256, 256, 0, stream>>>(x, res, out);
}

// Round 17
// 326.582 us; speedup vs baseline: 1.2004x; 1.0194x over previous
//
#include <hip/hip_runtime.h>
#include <cmath>

// ---- problem constants ----
#define DIMC   256
#define L_WIN  1023        // (131072-256)/128 + 1
#define M_VALID 4092       // 4*1023 tokens
#define M_PAD  4096
#define DI     1024        // D_INNER
#define TLEN   131072
#define SEG    32          // scan segment length
#define NSEG   32          // 32*32 = 1024 >= 1023
#define CBT    8           // tokens per conv_xproj block (r17: 16->8, 2 blocks/CU)

typedef __bf16 bf16x8 __attribute__((ext_vector_type(8)));
typedef __bf16 bf16x4 __attribute__((ext_vector_type(4)));
typedef float  f32x4  __attribute__((ext_vector_type(4)));

__device__ __forceinline__ float sigmoidf_(float x){ return 1.f/(1.f + __expf(-x)); }
__device__ __forceinline__ float softplusf_(float v){ return fmaxf(v,0.f) + log1pf(__expf(-fabsf(v))); }

// DPP rotate-add: pure-VALU cross-lane sum step (no LDS traffic)
template<int CTRL>
__device__ __forceinline__ float dpp_add(float x){
  int v = __builtin_amdgcn_update_dpp(0, __builtin_bit_cast(int, x), CTRL, 0xF, 0xF, true);
  return x + __builtin_bit_cast(float, v);
}

// ---------------- init: frame (blocks 0..4095) + weight bf16 convert (blocks 4096+) ----------------
__global__ __launch_bounds__(256) void init_kernel(const float* __restrict__ x, float* __restrict__ res,
    const float* __restrict__ a, __bf16* __restrict__ da, int na,
    const float* __restrict__ b, __bf16* __restrict__ db, int nb,
    const float* __restrict__ c, __bf16* __restrict__ dc, int nc)
{
  if (blockIdx.x < M_PAD){
    int m = blockIdx.x, j = threadIdx.x;
    float v = 0.f;
    if (m < M_VALID){
      int bb = m / L_WIN, l = m - bb*L_WIN;
      v = x[(size_t)bb*TLEN + l*128 + j];
    }
    res[(size_t)m*DIMC + j] = v;
    return;
  }
  int nblk = gridDim.x - M_PAD;
  int stride = nblk*256;
  int base = (blockIdx.x - M_PAD)*256 + threadIdx.x;
  for (int i = base; i < na; i += stride) da[i] = (__bf16)a[i];
  for (int i = base; i < nb; i += stride) db[i] = (__bf16)b[i];
  for (int i = base; i < nc; i += stride) dc[i] = (__bf16)c[i];
}

// ---------------- rmsnorm row of 256 -> bf16 ----------------
__global__ __launch_bounds__(256) void rms_kernel(const float* __restrict__ src, __bf16* __restrict__ dst,
                                                  const float* __restrict__ w){
  int m = blockIdx.x, j = threadIdx.x;
  float v = (m < M_VALID) ? src[(size_t)m*DIMC + j] : 0.f;
  float s = v*v;
  #pragma unroll
  for (int off = 32; off; off >>= 1) s += __shfl_down(s, off);
  __shared__ float ls[4];
  if ((threadIdx.x & 63) == 0) ls[threadIdx.x >> 6] = s;
  __syncthreads();
  float tot = ls[0] + ls[1] + ls[2] + ls[3];
  float scale = rsqrtf(tot * (1.f/DIMC) + 1e-5f);
  dst[(size_t)m*DIMC + j] = (__bf16)(v * scale * w[j]);
}

// ======== LDS-tiled bf16 MFMA GEMM: C[M x N] = A[M x K] * B[N x K]^T (+addsrc) ========
// NOTE: C/addsrc NOT __restrict__ — out_proj call is in-place (C==addsrc).
template<int WM, int WN, typename OutT>
__global__ __launch_bounds__(256) void gemm_tiled_kernel(const __bf16* __restrict__ A, const __bf16* __restrict__ B,
    OutT* C, const float* addsrc, int K, int ldc)
{
  constexpr int BM  = 32*WM;
  constexpr int BN  = 32*WN;
  constexpr int LDK = 72;
  __shared__ __bf16 As[BM*LDK];
  __shared__ __bf16 Bs[BN*LDK];
  int tid  = threadIdx.x;
  int lane = tid & 63, wv = tid >> 6;
  int row  = lane & 15, kq = lane >> 4;
  int m0 = blockIdx.x*BM, n0 = blockIdx.y*BN;
  int wmo = (wv >> 1)*(16*WM);
  int wno = (wv &  1)*(16*WN);
  f32x4 acc[WM][WN] = {};
  for (int kt = 0; kt < K; kt += 64){
    __syncthreads();
    #pragma unroll
    for (int r = 0; r < BM/32; ++r){
      int seg = r*256 + tid;
      int rw = seg >> 3, sb = seg & 7;
      *(bf16x8*)(As + rw*LDK + sb*8) = *(const bf16x8*)(A + (size_t)(m0 + rw)*K + kt + sb*8);
    }
    #pragma unroll
    for (int r = 0; r < BN/32; ++r){
      int seg = r*256 + tid;
      int rw = seg >> 3, sb = seg & 7;
      *(bf16x8*)(Bs + rw*LDK + sb*8) = *(const bf16x8*)(B + (size_t)(n0 + rw)*K + kt + sb*8);
    }
    __syncthreads();
    #pragma unroll
    for (int ks = 0; ks < 2; ++ks){
      bf16x8 af[WM], bfr[WN];
      #pragma unroll
      for (int i = 0; i < WM; ++i) af[i]  = *(const bf16x8*)(As + (wmo + i*16 + row)*LDK + ks*32 + kq*8);
      #pragma unroll
      for (int j = 0; j < WN; ++j) bfr[j] = *(const bf16x8*)(Bs + (wno + j*16 + row)*LDK + ks*32 + kq*8);
      #pragma unroll
      for (int i = 0; i < WM; ++i){
        #pragma unroll
        for (int j = 0; j < WN; ++j)
          acc[i][j] = __builtin_amdgcn_mfma_f32_16x16x32_bf16(af[i], bfr[j], acc[i][j], 0, 0, 0);
      }
    }
  }
  #pragma unroll
  for (int i = 0; i < WM; ++i){
    int cm = m0 + wmo + i*16 + kq*4;
    #pragma unroll
    for (int j = 0; j < WN; ++j){
      int cn = n0 + wno + j*16 + row;
      #pragma unroll
      for (int ii = 0; ii < 4; ++ii){
        size_t idx = (size_t)(cm + ii)*ldc + cn;
        float v = acc[i][j][ii];
        if (addsrc) v += addsrc[idx];
        C[idx] = (OutT)v;
      }
    }
  }
}

// ======== fused conv4+SiLU -> xproj MFMA (K-split) -> dt_proj+softplus ========
// r17: 8 tokens/block -> 512 blocks = 2 blocks/CU (2x occupancy of r16).
// MFMA tile keeps 16 rows; rows 8-15 read stale LDS and produce garbage only in
// discarded C rows (C row m depends only on A row m); writes masked to tok<CBT.
__global__ __launch_bounds__(256) void conv_xproj_dt_kernel(
  const __bf16* __restrict__ xz16, const float* __restrict__ cw, const float* __restrict__ cb,
  const __bf16* __restrict__ wxp, const float* __restrict__ dtw, const float* __restrict__ dtb,
  __bf16* __restrict__ u16, float* __restrict__ xdbl, __bf16* __restrict__ delta16)
{
  __shared__ __bf16 su[16][1032];     // rows 0..CBT-1 valid; +8 pad
  __shared__ float  sdt[CBT][17];
  __shared__ f32x4  spart[4][3][64];  // [kwave][tile][lane] partial xproj sums (12 KB)
  int tid = threadIdx.x;
  int m0 = blockIdx.x * CBT;
  // ---- phase A: causal depthwise conv4 + bias + SiLU (rolling 4-row register window) ----
  {
    int d = tid * 4;
    float w[4][4], bias[4];
    #pragma unroll
    for (int c = 0; c < 4; ++c){
      #pragma unroll
      for (int j = 0; j < 4; ++j) w[c][j] = cw[(d + c)*4 + j];
      bias[c] = cb[d + c];
    }
    bf16x4 zero4; zero4[0] = (__bf16)0.f; zero4[1] = (__bf16)0.f; zero4[2] = (__bf16)0.f; zero4[3] = (__bf16)0.f;
    bf16x4 rm3 = (m0 >= 3) ? *(const bf16x4*)(xz16 + (size_t)(m0-3)*2048 + d) : zero4;
    bf16x4 rm2 = (m0 >= 2) ? *(const bf16x4*)(xz16 + (size_t)(m0-2)*2048 + d) : zero4;
    bf16x4 rm1 = (m0 >= 1) ? *(const bf16x4*)(xz16 + (size_t)(m0-1)*2048 + d) : zero4;
    for (int ti = 0; ti < CBT; ++ti){
      int m = m0 + ti;
      bf16x4 cur = *(const bf16x4*)(xz16 + (size_t)m*2048 + d);  // pad rows are zeros
      float acc[4] = {0.f, 0.f, 0.f, 0.f};
      if (m < M_VALID){
        int b = m / L_WIN;
        int l = m - b*L_WIN;
        #pragma unroll
        for (int c = 0; c < 4; ++c) acc[c] = fmaf((float)cur[c], w[c][3], bias[c]);
        if (l >= 1){
          #pragma unroll
          for (int c = 0; c < 4; ++c) acc[c] = fmaf((float)rm1[c], w[c][2], acc[c]);
        }
        if (l >= 2){
          #pragma unroll
          for (int c = 0; c < 4; ++c) acc[c] = fmaf((float)rm2[c], w[c][1], acc[c]);
        }
        if (l >= 3){
          #pragma unroll
          for (int c = 0; c < 4; ++c) acc[c] = fmaf((float)rm3[c], w[c][0], acc[c]);
        }
        #pragma unroll
        for (int c = 0; c < 4; ++c) acc[c] = acc[c] * sigmoidf_(acc[c]);
      }
      bf16x4 o;
      #pragma unroll
      for (int c = 0; c < 4; ++c) o[c] = (__bf16)acc[c];
      *(bf16x4*)(u16 + (size_t)m*DI + d) = o;
      *(bf16x4*)(&su[ti][d]) = o;
      rm3 = rm2; rm2 = rm1; rm1 = cur;
    }
  }
  __syncthreads();
  // ---- phase B: xproj, CBT tokens x 48 outputs, K=1024 split across 4 waves ----
  {
    int lane = tid & 63, wv = tid >> 6;
    int row = lane & 15, kq = lane >> 4;
    int kbase = wv * 256;
    f32x4 acc0 = {0,0,0,0}, acc1 = {0,0,0,0}, acc2 = {0,0,0,0};
    const __bf16* B0 = wxp + (size_t)(row)*1024      + kbase + kq*8;
    const __bf16* B1 = wxp + (size_t)(16 + row)*1024 + kbase + kq*8;
    const __bf16* B2 = wxp + (size_t)(32 + row)*1024 + kbase + kq*8;
    #pragma unroll
    for (int k = 0; k < 256; k += 32){
      bf16x8 a = *(const bf16x8*)(&su[row][kbase + k + kq*8]);
      acc0 = __builtin_amdgcn_mfma_f32_16x16x32_bf16(a, *(const bf16x8*)(B0 + k), acc0, 0, 0, 0);
      acc1 = __builtin_amdgcn_mfma_f32_16x16x32_bf16(a, *(const bf16x8*)(B1 + k), acc1, 0, 0, 0);
      acc2 = __builtin_amdgcn_mfma_f32_16x16x32_bf16(a, *(const bf16x8*)(B2 + k), acc2, 0, 0, 0);
    }
    spart[wv][0][lane] = acc0;
    spart[wv][1][lane] = acc1;
    spart[wv][2][lane] = acc2;
  }
  __syncthreads();
  // ---- reduce partials, write xdbl + sdt (only valid tokens) ----
  if (tid < 192){
    int tno = tid >> 6, lane = tid & 63;
    int row = lane & 15, kq = lane >> 4;
    f32x4 sum = spart[0][tno][lane];
    sum += spart[1][tno][lane];
    sum += spart[2][tno][lane];
    sum += spart[3][tno][lane];
    #pragma unroll
    for (int i = 0; i < 4; ++i){
      int tok = kq*4 + i;
      if (tok < CBT){
        xdbl[(size_t)(m0 + tok)*48 + tno*16 + row] = sum[i];
        if (tno == 0) sdt[tok][row] = sum[i];
      }
    }
  }
  __syncthreads();
  // ---- phase C: dt_proj (K=16) + softplus -> delta16 ----
  {
    int d0 = tid * 4;
    float w[4][16], bias[4];
    #pragma unroll
    for (int c = 0; c < 4; ++c){
      #pragma unroll
      for (int q = 0; q < 16; ++q) w[c][q] = dtw[(d0 + c)*16 + q];
      bias[c] = dtb[d0 + c];
    }
    for (int t = 0; t < CBT; ++t){
      float acc[4] = {bias[0], bias[1], bias[2], bias[3]};
      #pragma unroll
      for (int r = 0; r < 16; ++r){
        float dv = sdt[t][r];
        #pragma unroll
        for (int c = 0; c < 4; ++c) acc[c] = fmaf(dv, w[c][r], acc[c]);
      }
      bf16x4 o;
      #pragma unroll
      for (int c = 0; c < 4; ++c) o[c] = (__bf16)softplusf_(acc[c]);
      *(bf16x4*)(delta16 + (size_t)(m0 + t)*DI + d0) = o;
    }
  }
}

// ================= chunked two-phase selective scan =================
__global__ __launch_bounds__(256) void scan_part1_kernel(
  const __bf16* __restrict__ u16, const __bf16* __restrict__ delta16,
  const float* __restrict__ xdbl, const float* __restrict__ Alog, float2* __restrict__ Pq)
{
  int bid = blockIdx.x;
  int s = bid & 31, dtile = (bid >> 5) & 63, b = bid >> 11;
  int d0 = dtile << 4;
  int tid = threadIdx.x;
  int c = tid >> 4, n = tid & 15;
  float A_dn = -__expf(Alog[(d0 + c)*16 + n]);
  __shared__ float2 sdd[16][SEG+2];   // (dlt, dlt*u)
  __shared__ float  sB [SEG][17];
  int t0 = s*SEG;
  int nt = L_WIN - t0; if (nt > SEG) nt = SEG;
  size_t base_m = (size_t)b*L_WIN + t0;
  for (int i2 = tid; i2 < 16*SEG; i2 += 256){
    int tt = i2 >> 4, dd = i2 & 15;
    float dlt = 0.f, du = 0.f, Bv = 0.f;
    if (tt < nt){
      size_t m = base_m + tt;
      dlt = (float)delta16[m*DI + d0 + dd];
      du  = dlt * (float)u16[m*DI + d0 + dd];
      Bv  = xdbl[m*48 + 16 + dd];
    }
    sdd[dd][tt] = make_float2(dlt, du);
    sB[tt][dd]  = Bv;
  }
  __syncthreads();
  float h = 0.f, P = 1.f;
  #pragma unroll 8
  for (int t = 0; t < SEG; ++t){
    float2 dd2 = sdd[c][t];
    float dA = __expf(dd2.x * A_dn);
    h = fmaf(dA, h, dd2.y * sB[t][n]);
    P *= dA;
  }
  Pq[(((size_t)b*NSEG + s) << 14) + d0*16 + tid] = make_float2(P, h);
}

__global__ __launch_bounds__(256) void scan_combine_kernel(const float2* __restrict__ Pq,
                                                           float* __restrict__ hstart)
{
  int idx = blockIdx.x*256 + threadIdx.x;
  int b = idx >> 14;
  int dn = idx & 16383;
  float hs = 0.f;
  #pragma unroll
  for (int s = 0; s < NSEG; ++s){
    size_t o = (((size_t)b*NSEG + s) << 14) + dn;
    hstart[o] = hs;
    float2 pq = Pq[o];
    hs = fmaf(pq.x, hs, pq.y);
  }
}

__global__ __launch_bounds__(256) void scan_part2_kernel(
  const __bf16* __restrict__ u16, const __bf16* __restrict__ delta16,
  const float* __restrict__ xdbl, const __bf16* __restrict__ xz16,
  const float* __restrict__ Alog, const float* __restrict__ Dp,
  const float* __restrict__ hstart, __bf16* __restrict__ y16)
{
  int bid = blockIdx.x;
  int s = bid & 31, dtile = (bid >> 5) & 63, b = bid >> 11;
  int d0 = dtile << 4;
  int tid = threadIdx.x;
  int c = tid >> 4, n = tid & 15;
  float A_dn = -__expf(Alog[(d0 + c)*16 + n]);
  __shared__ float2 sdd[16][SEG+2];   // (dlt, u)
  __shared__ float2 sBC[SEG][17];     // (B_n, C_n)
  __shared__ float  sy [16][SEG+1];
  __shared__ float  sD[16];
  if (tid < 16) sD[tid] = Dp[d0 + tid];
  int t0 = s*SEG;
  int nt = L_WIN - t0; if (nt > SEG) nt = SEG;
  size_t base_m = (size_t)b*L_WIN + t0;
  for (int i2 = tid; i2 < 16*SEG; i2 += 256){
    int tt = i2 >> 4, dd = i2 & 15;
    float dlt = 0.f, uu = 0.f, Bv = 0.f, Cv = 0.f;
    if (tt < nt){
      size_t m = base_m + tt;
      dlt = (float)delta16[m*DI + d0 + dd];
      uu  = (float)u16[m*DI + d0 + dd];
      Bv  = xdbl[m*48 + 16 + dd];
      Cv  = xdbl[m*48 + 32 + dd];
    }
    sdd[dd][tt] = make_float2(dlt, uu);
    sBC[tt][dd] = make_float2(Bv, Cv);
  }
  float h = hstart[(((size_t)b*NSEG + s) << 14) + d0*16 + tid];
  __syncthreads();
  #pragma unroll 8
  for (int t = 0; t < SEG; ++t){
    float2 dd2 = sdd[c][t];
    float dA = __expf(dd2.x * A_dn);
    float2 bc = sBC[t][n];
    h = fmaf(dA, h, dd2.x * dd2.y * bc.x);
    float pp = h * bc.y;
    pp = dpp_add<0xB1>(pp);    // xor1
    pp = dpp_add<0x4E>(pp);    // xor2
    pp = dpp_add<0x141>(pp);   // row_half_mirror
    pp = dpp_add<0x128>(pp);   // row_ror:8
    if (n == 0) sy[c][t] = pp;
  }
  __syncthreads();
  for (int i2 = tid; i2 < 16*nt; i2 += 256){
    int tt = i2 >> 4, dd = i2 & 15;
    size_t m = base_m + tt;
    float uv = sdd[dd][tt].y;
    float zv = (float)xz16[m*2048 + 1024 + d0 + dd];
    float yv = (sy[dd][tt] + uv * sD[dd]) * (zv * sigmoidf_(zv));
    y16[m*DI + d0 + dd] = (__bf16)yv;
  }
}

// ---------------- overlap-add fold + passthrough ----------------
__global__ __launch_bounds__(256) void fold_kernel(const float* __restrict__ x, const float* __restrict__ r,
                                                   float* __restrict__ out){
  int i = blockIdx.x*256 + threadIdx.x;
  int b = i >> 17;
  int t = i & (TLEN - 1);
  float acc = x[i];
  int l1 = t >> 7;
  int j  = t & 127;
  if (l1 < L_WIN) acc += r[((size_t)b*L_WIN + l1)*DIMC + j] * ((float)j * (1.f/127.f));
  if (l1 >= 1)    acc += r[((size_t)b*L_WIN + l1 - 1)*DIMC + j + 128] * ((float)(127 - j) * (1.f/127.f));
  out[i] = acc;
}

extern "C" void kernel_launch(void* const* d_in, const int* in_sizes, int n_in,
                              void* d_out, int out_size, void* d_ws, size_t ws_size,
                              hipStream_t stream)
{
  (void)in_sizes; (void)n_in; (void)out_size; (void)ws_size;
  const float* x      = (const float*)d_in[0];
  const float* in_w   = (const float*)d_in[1];
  const float* conv_w = (const float*)d_in[2];
  const float* conv_b = (const float*)d_in[3];
  const float* xp_w   = (const float*)d_in[4];
  const float* dt_w   = (const float*)d_in[5];
  const float* dt_b   = (const float*)d_in[6];
  const float* A_log  = (const float*)d_in[7];
  const float* Dp     = (const float*)d_in[8];
  const float* out_w  = (const float*)d_in[9];
  const float* norm_w = (const float*)d_in[10];
  float* out = (float*)d_out;

  // workspace layout (~74 MB; ws is 256 MiB)
  char* p = (char*)d_ws;
  auto alloc = [&](size_t bytes)->void*{ void* r = (void*)p; p += (bytes + 255) & ~(size_t)255; return r; };
  float*  res    = (float*) alloc((size_t)M_PAD*DIMC*4);        // 4 MB
  __bf16* hn16   = (__bf16*)alloc((size_t)M_PAD*DIMC*2);        // 2 MB
  __bf16* xz16   = (__bf16*)alloc((size_t)M_PAD*2048*2);        // 16 MB
  __bf16* u16    = (__bf16*)alloc((size_t)M_PAD*DI*2);          // 8 MB
  float*  xdbl   = (float*) alloc((size_t)M_PAD*48*4);          // 0.75 MB
  __bf16* delta16= (__bf16*)alloc((size_t)M_PAD*DI*2);          // 8 MB
  __bf16* y16    = (__bf16*)alloc((size_t)M_PAD*DI*2);          // 8 MB
  float2* Pq     = (float2*)alloc((size_t)4*NSEG*16384*8);      // 16 MB
  float*  hstart = (float*) alloc((size_t)4*NSEG*16384*4);      // 8 MB
  __bf16* w_in16 = (__bf16*)alloc((size_t)2*2048*256*2);        // 2 MB
  __bf16* w_xp16 = (__bf16*)alloc((size_t)2*48*1024*2);         // 0.19 MB
  __bf16* w_out16= (__bf16*)alloc((size_t)2*256*1024*2);        // 1 MB

  init_kernel<<<M_PAD + 512, 256, 0, stream>>>(x, res,
                                               in_w, w_in16, 2*2048*256,
                                               xp_w, w_xp16, 2*48*1024,
                                               out_w, w_out16, 2*256*1024);

  for (int i = 0; i < 2; ++i){
    rms_kernel<<<M_PAD, 256, 0, stream>>>(res, hn16, norm_w + i*256);
    gemm_tiled_kernel<4, 4, __bf16><<<dim3(32, 16), 256, 0, stream>>>(hn16, w_in16 + (size_t)i*524288, xz16, nullptr, 256, 2048);
    conv_xproj_dt_kernel<<<M_PAD/CBT, 256, 0, stream>>>(xz16, conv_w + i*4096, conv_b + i*1024,
                                                        w_xp16 + (size_t)i*49152, dt_w + i*16384, dt_b + i*1024,
                                                        u16, xdbl, delta16);
    scan_part1_kernel<<<8192, 256, 0, stream>>>(u16, delta16, xdbl, A_log + i*16384, Pq);
    scan_combine_kernel<<<256, 256, 0, stream>>>(Pq, hstart);
    scan_part2_kernel<<<8192, 256, 0, stream>>>(u16, delta16, xdbl, xz16, A_log + i*16384, Dp + i*1024,
                                                hstart, y16);
    gemm_tiled_kernel<2, 2, float><<<dim3(64, 4), 256, 0, stream>>>(y16, w_out16 + (size_t)i*262144, res, res, 1024, 256);
  }
  fold_kernel<<<TLEN*4/256, 256, 0, stream>>>(x, res, out);
}